// Round 1
// baseline (647.280 us; speedup 1.0000x reference)
//
#include <hip/hip_runtime.h>

typedef __bf16 bf16_t;
typedef __bf16 bf16x8 __attribute__((ext_vector_type(8)));
typedef __bf16 bf16x4 __attribute__((ext_vector_type(4)));
typedef float  f32x4  __attribute__((ext_vector_type(4)));
typedef int    i32x4  __attribute__((ext_vector_type(4)));

#define PL 136   // padded row stride (elems) for [t][128] bf16 tiles (272B = 16B-aligned)
#define PX 264   // padded row stride (elems) for [t][256] bf16 tiles

__device__ __forceinline__ f32x4 mfma16(bf16x8 a, bf16x8 b, f32x4 c) {
    return __builtin_amdgcn_mfma_f32_16x16x32_bf16(a, b, c, 0, 0, 0);
}

// ---------------- merged prep: weight conversion + conditioning ----------------
__device__ __forceinline__ void conv_elem(const float* __restrict__ src,
                                          bf16_t* __restrict__ dst,
                                          int idx, int M, int K) {
    int MK = M * K;
    int lay = idx / MK;
    int r = idx - lay * MK;
    int j = r & 7, lane = (r >> 3) & 63, rest = r >> 9;
    int KB = K >> 5;
    int kb = rest % KB, mt = rest / KB;
    int m = mt * 16 + (lane & 15);
    int k = kb * 32 + ((lane >> 4) << 3) + j;
    dst[idx] = (bf16_t)src[(size_t)lay * MK + m * K + k];
}

__global__ void k_prep(const float* __restrict__ rw, const float* __restrict__ kw,
                       const float* __restrict__ s1w, const float* __restrict__ s2w,
                       const float* __restrict__ e1w, const float* __restrict__ dwt,
                       const float* __restrict__ cond_w, const float* __restrict__ end2_w,
                       const float* __restrict__ end2_b, const float* __restrict__ en,
                       bf16_t* __restrict__ Ares, bf16_t* __restrict__ Askp,
                       bf16_t* __restrict__ A1, bf16_t* __restrict__ A2,
                       bf16_t* __restrict__ Ae, bf16_t* __restrict__ Adil,
                       float* __restrict__ cond_all, float* __restrict__ cond2) {
    __shared__ f32x4 en_s[1024];
    if (blockIdx.x >= 13952) {
        // conditioning: bi in [0,124)
        int bi = blockIdx.x - 13952;
        int i = bi >> 2, n = bi & 3, o = threadIdx.x;
        const f32x4* ep = (const f32x4*)(en + (size_t)n * 4096);
        for (int idx = threadIdx.x; idx < 1024; idx += 256) en_s[idx] = ep[idx];
        __syncthreads();
        const float* W = (i < 30) ? cond_w + ((size_t)i * 256 + o) * 256
                                  : end2_w + (size_t)o * 256;
        f32x4 a0 = {0.f,0.f,0.f,0.f}, a1 = a0, a2 = a0, a3 = a0;
        for (int c = 0; c < 256; c += 4) {
            f32x4 wv = *(const f32x4*)(W + c);
            #pragma unroll
            for (int cc = 0; cc < 4; ++cc) {
                float wf = wv[cc];
                a0 += wf * en_s[(c + cc) * 4 + 0];
                a1 += wf * en_s[(c + cc) * 4 + 1];
                a2 += wf * en_s[(c + cc) * 4 + 2];
                a3 += wf * en_s[(c + cc) * 4 + 3];
            }
        }
        float bias = (i < 30) ? 0.f : end2_b[o];
        float* dst = (i < 30) ? cond_all + (((size_t)i * 4 + n) * 256 + o) * 16
                              : cond2 + ((size_t)n * 256 + o) * 16;
        f32x4* d4 = (f32x4*)dst;
        d4[0] = a0 + bias; d4[1] = a1 + bias; d4[2] = a2 + bias; d4[3] = a3 + bias;
        return;
    }
    int idx = blockIdx.x * 256 + threadIdx.x;
    if (idx < 491520) { conv_elem(rw, Ares, idx, 128, 128); return; }
    idx -= 491520;
    if (idx < 983040) { conv_elem(kw, Askp, idx, 256, 128); return; }
    idx -= 983040;
    if (idx < 32768) { conv_elem(s1w, A1, idx, 128, 256); return; }
    idx -= 32768;
    if (idx < 32768) { conv_elem(s2w, A2, idx, 256, 128); return; }
    idx -= 32768;
    if (idx < 65536) { conv_elem(e1w, Ae, idx, 256, 256); return; }
    idx -= 65536;
    {   // dil_w -> per-layer A[256][256]
        int lay = idx >> 16, r = idx & 65535;
        int j = r & 7, lane = (r >> 3) & 63, rest = r >> 9;
        int kb = rest & 7, mt = rest >> 3;
        int m = mt * 16 + (lane & 15);
        int k = kb * 32 + ((lane >> 4) << 3) + j;
        float v = (k < 128) ? dwt[(((size_t)lay * 256 + m) * 128 + k) * 2]
                            : dwt[(((size_t)lay * 256 + m) * 128 + (k - 128)) * 2 + 1];
        Adil[(size_t)lay * 65536 + r] = (bf16_t)v;
    }
}

// ---------------- start: l0 = start1@x ; s0 = start2@l0 (t>=4096) ----------------
__global__ __launch_bounds__(512, 4) void k_start(
    const float* __restrict__ x, bf16_t* __restrict__ la, float* __restrict__ sbuf,
    const bf16_t* __restrict__ A1, const bf16_t* __restrict__ A2, int t_base)
{
    __shared__ __align__(16) bf16_t xt[64 * PX];
    __shared__ __align__(16) bf16_t l0[64 * PL];
    int tid = threadIdx.x;
    int n = blockIdx.y, t0 = t_base + blockIdx.x * 64;
    int lane = tid & 63, w = tid >> 6, i16 = lane & 15, q = lane >> 4;
    f32x4 z = {0.f,0.f,0.f,0.f};
    {
        int t = tid & 63;
        for (int c = tid >> 6; c < 256; c += 8)
            xt[t * PX + c] = (bf16_t)x[((size_t)n * 256 + c) * 8192 + t0 + t];
    }
    __syncthreads();
    f32x4 acc[4] = {z,z,z,z};
    #pragma unroll
    for (int kb = 0; kb < 8; ++kb) {
        int koff = kb * 32 + q * 8;
        bf16x8 bf[4];
        #pragma unroll
        for (int nt = 0; nt < 4; ++nt)
            bf[nt] = *(const bf16x8*)(xt + (nt * 16 + i16) * PX + koff);
        bf16x8 af = *(const bf16x8*)(A1 + (((size_t)w * 8 + kb) * 64 + lane) * 8);
        #pragma unroll
        for (int nt = 0; nt < 4; ++nt) acc[nt] = mfma16(af, bf[nt], acc[nt]);
    }
    #pragma unroll
    for (int nt = 0; nt < 4; ++nt)
        #pragma unroll
        for (int j = 0; j < 4; ++j)
            l0[(nt * 16 + i16) * PL + w * 16 + q * 4 + j] = (bf16_t)acc[nt][j];
    __syncthreads();
    {
        int r = tid >> 4, col = (tid & 15) * 8;
        #pragma unroll
        for (int p = 0; p < 2; ++p) {
            int rr = r + p * 32;
            *(i32x4*)(la + ((size_t)n * 8192 + t0 + rr) * 128 + col) =
                *(const i32x4*)(l0 + rr * PL + col);
        }
    }
    if (t0 >= 4096) {
        f32x4 a2[2][4] = {{z,z,z,z},{z,z,z,z}};
        #pragma unroll
        for (int kb = 0; kb < 4; ++kb) {
            int koff = kb * 32 + q * 8;
            bf16x8 bf[4];
            #pragma unroll
            for (int nt = 0; nt < 4; ++nt)
                bf[nt] = *(const bf16x8*)(l0 + (nt * 16 + i16) * PL + koff);
            #pragma unroll
            for (int mt2 = 0; mt2 < 2; ++mt2) {
                bf16x8 af = *(const bf16x8*)(A2 + ((((size_t)2 * w + mt2) * 4 + kb) * 64 + lane) * 8);
                #pragma unroll
                for (int nt = 0; nt < 4; ++nt) a2[mt2][nt] = mfma16(af, bf[nt], a2[mt2][nt]);
            }
        }
        float* sp = sbuf + (size_t)n * 256 * 4096 + (t0 - 4096);
        #pragma unroll
        for (int mt2 = 0; mt2 < 2; ++mt2)
            #pragma unroll
            for (int nt = 0; nt < 4; ++nt)
                #pragma unroll
                for (int j = 0; j < 4; ++j) {
                    int o = (2 * w + mt2) * 16 + q * 4 + j;
                    sp[(size_t)o * 4096 + nt * 16 + i16] = a2[mt2][nt][j];
                }
    }
}

// ---------------- single layer, TT=32, merged staging for dil<32 ----------------
// USEG=1: stream bf16 gate tile to Gl in MFMA B-FRAGMENT order; skip GEMM deferred to k_skip.
// G tile layout (per 32x128 tile, 4096 elems): elem ((nt*4+kb)*64 + lane)*8 + j
//   = gate[t = nt*16 + (lane&15)][c = kb*32 + (lane>>4)*8 + j]
template<int USEG>
__global__ __launch_bounds__(512, 8) void k_layer(
    const bf16_t* __restrict__ l_in, bf16_t* __restrict__ l_out,
    float* __restrict__ sbuf, bf16_t* __restrict__ Gl,
    const bf16_t* __restrict__ Ad, const bf16_t* __restrict__ Ar,
    const bf16_t* __restrict__ Ak, const float* __restrict__ condL,
    int dil, int t_base, int do_res)
{
    __shared__ __align__(16) bf16_t smA[64 * PL];   // staging (cur|del or combined)
    __shared__ __align__(16) bf16_t sm2[32 * PL];   // gate
    int tid = threadIdx.x;
    int n = blockIdx.y, t0 = t_base + blockIdx.x * 32;
    int lane = tid & 63, w = tid >> 6, i16 = lane & 15, q = lane >> 4;
    f32x4 z = {0.f,0.f,0.f,0.f};
    const float* cond = condL + (size_t)n * 4096;
    int r = tid >> 4, col = (tid & 15) * 8;
    size_t base = (size_t)n * 8192;
    const bf16_t* curp;
    const bf16_t* delp;
    if (dil < 32) {
        // combined window rows [t0-dil, t0+32): del row r = smA[r], cur row r = smA[r+dil]
        int cnt = (32 + dil) * 16;
        for (int idx = tid; idx < cnt; idx += 512) {
            int rr = idx >> 4, c2 = (idx & 15) * 8;
            *(i32x4*)(smA + rr * PL + c2) =
                *(const i32x4*)(l_in + (base + t0 - dil + rr) * 128 + c2);
        }
        delp = smA; curp = smA + dil * PL;
    } else {
        *(i32x4*)(smA + r * PL + col) =
            *(const i32x4*)(l_in + (base + t0 + r) * 128 + col);
        int gp = t0 - dil + r;
        i32x4 v = {0, 0, 0, 0};
        if (gp >= 0) v = *(const i32x4*)(l_in + (base + gp) * 128 + col);
        *(i32x4*)(smA + (32 + r) * PL + col) = v;
        curp = smA; delp = smA + 32 * PL;
    }
    __syncthreads();

    // GEMM1: d = [W0 W1] @ [l_del; l_cur], M=256 K=256, N=32
    f32x4 accs[2] = {z,z}, acct[2] = {z,z};
    const bf16x8* AdF = (const bf16x8*)Ad;
    #pragma unroll
    for (int kb = 0; kb < 8; ++kb) {
        const bf16_t* bsrc = (kb < 4) ? delp : curp;
        int koff = (kb & 3) * 32 + q * 8;
        bf16x8 bf[2];
        #pragma unroll
        for (int nt = 0; nt < 2; ++nt)
            bf[nt] = *(const bf16x8*)(bsrc + (nt * 16 + i16) * PL + koff);
        bf16x8 a_s = AdF[((size_t)w * 8 + kb) * 64 + lane];
        bf16x8 a_t = AdF[((size_t)(w + 8) * 8 + kb) * 64 + lane];
        #pragma unroll
        for (int nt = 0; nt < 2; ++nt) {
            accs[nt] = mfma16(a_s, bf[nt], accs[nt]);
            acct[nt] = mfma16(a_t, bf[nt], acct[nt]);
        }
    }
    int c_base = w * 16 + q * 4;
    {   // gate in-register -> sm2
        float cv_s[4], cv_t[4];
        #pragma unroll
        for (int j = 0; j < 4; ++j) {
            cv_s[j] = cond[(c_base + j) * 16 + i16];
            cv_t[j] = cond[(c_base + j + 128) * 16 + i16];
        }
        #pragma unroll
        for (int nt = 0; nt < 2; ++nt) {
            bf16x4 g4;
            #pragma unroll
            for (int j = 0; j < 4; ++j) {
                float vlo = accs[nt][j] + cv_s[j];
                float vhi = acct[nt][j] + cv_t[j];
                float sg = 1.0f / (1.0f + __expf(-vlo));
                float th = 1.0f - 2.0f / (1.0f + __expf(2.0f * vhi));
                g4[j] = (bf16_t)(sg * th);
            }
            *(bf16x4*)(sm2 + (nt * 16 + i16) * PL + c_base) = g4;
        }
    }
    __syncthreads();   // gate ready; all GEMM1 LDS reads done

    if (USEG) {
        if (t0 >= 4096) {   // stream gate tile to G in fragment order (coalesced 16B/thread)
            int tt = ((tid & 256) >> 4) + (tid & 15);               // (tid>>8)*16 + i16
            int cc = ((tid >> 6) & 3) * 32 + ((tid >> 4) & 3) * 8;  // kb*32 + qf*8
            bf16x8 gv = *(const bf16x8*)(sm2 + tt * PL + cc);
            *(bf16x8*)(Gl + ((size_t)n * 4096 + (t0 - 4096)) * 128 + tid * 8) = gv;
        }
    }

    f32x4 acc2[2] = {z,z};
    const bf16x8* ArF = (const bf16x8*)Ar;
    if (do_res || !USEG) {
        int do_skip = (!USEG) && (t0 >= 4096);
        f32x4 acc3[2][2] = {{z,z},{z,z}};
        const bf16x8* AkF = (const bf16x8*)Ak;
        #pragma unroll
        for (int kb = 0; kb < 4; ++kb) {
            int koff = kb * 32 + q * 8;
            bf16x8 bf[2];
            #pragma unroll
            for (int nt = 0; nt < 2; ++nt)
                bf[nt] = *(const bf16x8*)(sm2 + (nt * 16 + i16) * PL + koff);
            if (do_res) {
                bf16x8 ar = ArF[((size_t)w * 4 + kb) * 64 + lane];
                #pragma unroll
                for (int nt = 0; nt < 2; ++nt) acc2[nt] = mfma16(ar, bf[nt], acc2[nt]);
            }
            if (do_skip) {
                #pragma unroll
                for (int mt2 = 0; mt2 < 2; ++mt2) {
                    bf16x8 ak = AkF[((size_t)(2 * w + mt2) * 4 + kb) * 64 + lane];
                    #pragma unroll
                    for (int nt = 0; nt < 2; ++nt)
                        acc3[mt2][nt] = mfma16(ak, bf[nt], acc3[mt2][nt]);
                }
            }
        }
        if (do_skip) {
            float* sp = sbuf + (size_t)n * 256 * 4096 + (t0 - 4096);
            #pragma unroll
            for (int mt2 = 0; mt2 < 2; ++mt2)
                #pragma unroll
                for (int nt = 0; nt < 2; ++nt)
                    #pragma unroll
                    for (int j = 0; j < 4; ++j) {
                        int o = (2 * w + mt2) * 16 + q * 4 + j;
                        sp[(size_t)o * 4096 + nt * 16 + i16] += acc3[mt2][nt][j];
                    }
        }
    }

    if (do_res) {
        // sum = f32(l_cur) + res in regs; direct 8B store (no LDS roundtrip, no extra barriers)
        #pragma unroll
        for (int nt = 0; nt < 2; ++nt) {
            int trow = (nt * 16 + i16) * PL;
            bf16x4 lv = *(const bf16x4*)(curp + trow + c_base);
            bf16x4 o4;
            #pragma unroll
            for (int j = 0; j < 4; ++j)
                o4[j] = (bf16_t)((float)lv[j] + acc2[nt][j]);
            *(bf16x4*)(l_out + (base + t0 + nt * 16 + i16) * 128 + c_base) = o4;
        }
    }
}

// ---------------- deferred skip mega-GEMM: s += sum_i skip_i @ g_i ----------------
// TT=64, fragment-order G (linear, conflict-free LDS), depth-4 register prefetch ring,
// raw s_barrier + lgkmcnt(0) (NO vmcnt drain) so global prefetch stays in flight.
__global__ __launch_bounds__(512, 4) void k_skip(
    const bf16_t* __restrict__ G, float* __restrict__ sbuf,
    const bf16_t* __restrict__ Askp)
{
    __shared__ __align__(16) bf16_t gbuf[2][8192];
    int tid = threadIdx.x;
    int n = blockIdx.y, t0 = blockIdx.x * 64;
    int lane = tid & 63, w = tid >> 6, i16 = lane & 15, q = lane >> 4;
    f32x4 z = {0.f,0.f,0.f,0.f};
    f32x4 acc[2][4] = {{z,z,z,z},{z,z,z,z}};
    const size_t GLS = (size_t)4 * 4096 * 128;   // per-layer stride in G (elems)
    const bf16_t* gb = G + ((size_t)n * 4096 + t0) * 128 + tid * 8;
    i32x4 v0[4], v1[4];
    #pragma unroll
    for (int d = 0; d < 4; ++d) {
        v0[d] = *(const i32x4*)(gb + (size_t)d * GLS);
        v1[d] = *(const i32x4*)(gb + (size_t)d * GLS + 4096);
    }
    // stage layer 0, refill slot 0 with layer 4
    *(i32x4*)(gbuf[0] + tid * 8) = v0[0];
    *(i32x4*)(gbuf[0] + 4096 + tid * 8) = v1[0];
    v0[0] = *(const i32x4*)(gb + (size_t)4 * GLS);
    v1[0] = *(const i32x4*)(gb + (size_t)4 * GLS + 4096);
    __syncthreads();   // prologue: single full drain
    #pragma unroll 1
    for (int i = 0; i < 30; ++i) {
        const bf16x8* AkF = (const bf16x8*)(Askp + (size_t)i * 32768);
        const bf16_t* gB = gbuf[i & 1];
        #pragma unroll
        for (int kb = 0; kb < 4; ++kb) {
            bf16x8 ak0 = AkF[((size_t)(2 * w) * 4 + kb) * 64 + lane];
            bf16x8 ak1 = AkF[((size_t)(2 * w + 1) * 4 + kb) * 64 + lane];
            #pragma unroll
            for (int nt = 0; nt < 4; ++nt) {
                bf16x8 bf = *(const bf16x8*)(gB + (nt >> 1) * 4096 +
                                             (((nt & 1) * 4 + kb) * 64 + lane) * 8);
                acc[0][nt] = mfma16(ak0, bf, acc[0][nt]);
                acc[1][nt] = mfma16(ak1, bf, acc[1][nt]);
            }
        }
        if (i + 1 < 30) {
            int s = (i + 1) & 3;
            bf16_t* db = gbuf[(i + 1) & 1];
            *(i32x4*)(db + tid * 8) = v0[s];
            *(i32x4*)(db + 4096 + tid * 8) = v1[s];
            if (i + 5 < 30) {
                v0[s] = *(const i32x4*)(gb + (size_t)(i + 5) * GLS);
                v1[s] = *(const i32x4*)(gb + (size_t)(i + 5) * GLS + 4096);
            }
            // write-visibility barrier WITHOUT vmcnt drain: prefetches stay in flight
            asm volatile("s_waitcnt lgkmcnt(0)" ::: "memory");
            __builtin_amdgcn_sched_barrier(0);
            __builtin_amdgcn_s_barrier();
            __builtin_amdgcn_sched_barrier(0);
        }
    }
    float* sp = sbuf + (size_t)n * 256 * 4096 + t0;
    #pragma unroll
    for (int mt2 = 0; mt2 < 2; ++mt2)
        #pragma unroll
        for (int nt = 0; nt < 4; ++nt)
            #pragma unroll
            for (int j = 0; j < 4; ++j) {
                int o = (2 * w + mt2) * 16 + q * 4 + j;
                sp[(size_t)o * 4096 + nt * 16 + i16] += acc[mt2][nt][j];
            }
}

// ---------------- end: out = relu(end1@relu(s) + b1 + cond2_tiled) ----------------
__global__ __launch_bounds__(512) void k_end(
    const float* __restrict__ sbuf, float* __restrict__ out,
    const bf16_t* __restrict__ Ae, const float* __restrict__ cond2,
    const float* __restrict__ b1)
{
    __shared__ __align__(16) bf16_t st[64 * PX];
    __shared__ float c2[4096];
    __shared__ float b1s[256];
    int tid = threadIdx.x;
    int n = blockIdx.y, t0 = blockIdx.x * 64;
    int lane = tid & 63, w = tid >> 6, i16 = lane & 15, q = lane >> 4;
    f32x4 z = {0.f,0.f,0.f,0.f};
    {
        int t = tid & 63;
        for (int c = tid >> 6; c < 256; c += 8) {
            float v = sbuf[((size_t)n * 256 + c) * 4096 + t0 + t];
            st[t * PX + c] = (bf16_t)fmaxf(v, 0.f);
        }
        const f32x4* cc = (const f32x4*)(cond2 + (size_t)n * 4096);
        for (int idx = tid; idx < 1024; idx += 512) ((f32x4*)c2)[idx] = cc[idx];
        if (tid < 64) ((f32x4*)b1s)[tid] = ((const f32x4*)b1)[tid];
    }
    __syncthreads();
    f32x4 acc[2][4] = {{z,z,z,z},{z,z,z,z}};
    #pragma unroll
    for (int kb = 0; kb < 8; ++kb) {
        int koff = kb * 32 + q * 8;
        bf16x8 bf[4];
        #pragma unroll
        for (int nt = 0; nt < 4; ++nt)
            bf[nt] = *(const bf16x8*)(st + (nt * 16 + i16) * PX + koff);
        #pragma unroll
        for (int mt2 = 0; mt2 < 2; ++mt2) {
            bf16x8 af = *(const bf16x8*)(Ae + ((((size_t)2 * w + mt2) * 8 + kb) * 64 + lane) * 8);
            #pragma unroll
            for (int nt = 0; nt < 4; ++nt) acc[mt2][nt] = mfma16(af, bf[nt], acc[mt2][nt]);
        }
    }
    #pragma unroll
    for (int mt2 = 0; mt2 < 2; ++mt2)
        #pragma unroll
        for (int j = 0; j < 4; ++j) {
            int o = (2 * w + mt2) * 16 + q * 4 + j;
            float bb = b1s[o] + c2[o * 16 + i16];
            #pragma unroll
            for (int nt = 0; nt < 4; ++nt) {
                float v = acc[mt2][nt][j] + bb;
                out[((size_t)n * 256 + o) * 4096 + t0 + nt * 16 + i16] = fmaxf(v, 0.f);
            }
        }
}

extern "C" void kernel_launch(void* const* d_in, const int* in_sizes, int n_in,
                              void* d_out, int out_size, void* d_ws, size_t ws_size,
                              hipStream_t stream) {
    const float* x   = (const float*)d_in[0];
    const float* en  = (const float*)d_in[1];
    const float* s1w = (const float*)d_in[2];
    const float* s2w = (const float*)d_in[3];
    const float* cw  = (const float*)d_in[4];
    const float* dw  = (const float*)d_in[5];
    const float* rw  = (const float*)d_in[6];
    const float* kw  = (const float*)d_in[7];
    const float* e1w = (const float*)d_in[8];
    const float* e1b = (const float*)d_in[9];
    const float* e2w = (const float*)d_in[10];
    const float* e2b = (const float*)d_in[11];
    float* out = (float*)d_out;

    char* p = (char*)d_ws;
    auto take = [&](size_t bytes) {
        char* r = p;
        p += (bytes + 255) & ~(size_t)255;
        return r;
    };
    bf16_t* A1   = (bf16_t*)take((size_t)128 * 256 * 2);
    bf16_t* A2   = (bf16_t*)take((size_t)256 * 128 * 2);
    bf16_t* Ae   = (bf16_t*)take((size_t)256 * 256 * 2);
    bf16_t* Adil = (bf16_t*)take((size_t)30 * 65536 * 2);
    bf16_t* Ares = (bf16_t*)take((size_t)30 * 16384 * 2);
    bf16_t* Askp = (bf16_t*)take((size_t)30 * 32768 * 2);
    float*  condA= (float*)take((size_t)30 * 16384 * 4);
    float*  cond2= (float*)take((size_t)16384 * 4);
    bf16_t* la   = (bf16_t*)take((size_t)4 * 8192 * 128 * 2);
    bf16_t* lb   = (bf16_t*)take((size_t)4 * 8192 * 128 * 2);
    float*  sbuf = (float*)take((size_t)4 * 256 * 4096 * 4);
    bf16_t* G    = (bf16_t*)take((size_t)30 * 4 * 4096 * 128 * 2);  // last
    bool useG = ((size_t)(p - (char*)d_ws) <= ws_size);

    k_prep<<<14076, 256, 0, stream>>>(rw, kw, s1w, s2w, e1w, dw,
                                      cw, e2w, e2b, en,
                                      Ares, Askp, A1, A2, Ae, Adil, condA, cond2);

    // causal trim table (host)
    int a[30];
    a[29] = 4096;
    for (int i = 28; i >= 0; --i) {
        int nx = a[i + 1] - (1 << ((i + 1) % 10));
        a[i] = nx < 4096 ? (nx & ~63) : 4096;
    }

    k_start<<<dim3(127, 4), 512, 0, stream>>>(x, la, sbuf, A1, A2, 64);

    bf16_t* src = la;
    bf16_t* dst = lb;
    for (int i = 0; i < 30; ++i) {
        dim3 grid((8192 - a[i]) / 32, 4);
        if (useG)
            k_layer<1><<<grid, 512, 0, stream>>>(src, dst, sbuf,
                G + (size_t)i * 4 * 4096 * 128,
                Adil + (size_t)i * 65536, Ares + (size_t)i * 16384,
                Askp + (size_t)i * 32768, condA + (size_t)i * 16384,
                1 << (i % 10), a[i], i < 29 ? 1 : 0);
        else
            k_layer<0><<<grid, 512, 0, stream>>>(src, dst, sbuf, (bf16_t*)nullptr,
                Adil + (size_t)i * 65536, Ares + (size_t)i * 16384,
                Askp + (size_t)i * 32768, condA + (size_t)i * 16384,
                1 << (i % 10), a[i], i < 29 ? 1 : 0);
        bf16_t* t = src; src = dst; dst = t;
    }
    if (useG)
        k_skip<<<dim3(64, 4), 512, 0, stream>>>(G, sbuf, Askp);
    k_end<<<dim3(64, 4), 512, 0, stream>>>(sbuf, out, Ae, cond2, e1b);
}

// Round 2
// 638.887 us; speedup vs baseline: 1.0131x; 1.0131x over previous
//
#include <hip/hip_runtime.h>

typedef __bf16 bf16_t;
typedef __bf16 bf16x8 __attribute__((ext_vector_type(8)));
typedef __bf16 bf16x4 __attribute__((ext_vector_type(4)));
typedef float  f32x4  __attribute__((ext_vector_type(4)));
typedef int    i32x4  __attribute__((ext_vector_type(4)));

#define PL 136   // padded row stride (elems) for [t][128] bf16 tiles (272B = 16B-aligned)
#define PX 264   // padded row stride (elems) for [t][256] bf16 tiles

__device__ __forceinline__ f32x4 mfma16(bf16x8 a, bf16x8 b, f32x4 c) {
    return __builtin_amdgcn_mfma_f32_16x16x32_bf16(a, b, c, 0, 0, 0);
}

// ---------------- merged prep: weight conversion + conditioning ----------------
__device__ __forceinline__ void conv_elem(const float* __restrict__ src,
                                          bf16_t* __restrict__ dst,
                                          int idx, int M, int K) {
    int MK = M * K;
    int lay = idx / MK;
    int r = idx - lay * MK;
    int j = r & 7, lane = (r >> 3) & 63, rest = r >> 9;
    int KB = K >> 5;
    int kb = rest % KB, mt = rest / KB;
    int m = mt * 16 + (lane & 15);
    int k = kb * 32 + ((lane >> 4) << 3) + j;
    dst[idx] = (bf16_t)src[(size_t)lay * MK + m * K + k];
}

__global__ void k_prep(const float* __restrict__ rw, const float* __restrict__ kw,
                       const float* __restrict__ s1w, const float* __restrict__ s2w,
                       const float* __restrict__ e1w, const float* __restrict__ dwt,
                       const float* __restrict__ cond_w, const float* __restrict__ end2_w,
                       const float* __restrict__ end2_b, const float* __restrict__ en,
                       bf16_t* __restrict__ Ares, bf16_t* __restrict__ Askp,
                       bf16_t* __restrict__ A1, bf16_t* __restrict__ A2,
                       bf16_t* __restrict__ Ae, bf16_t* __restrict__ Adil,
                       float* __restrict__ cond_all, float* __restrict__ cond2) {
    __shared__ f32x4 en_s[1024];
    if (blockIdx.x >= 13952) {
        // conditioning: bi in [0,124)
        int bi = blockIdx.x - 13952;
        int i = bi >> 2, n = bi & 3, o = threadIdx.x;
        const f32x4* ep = (const f32x4*)(en + (size_t)n * 4096);
        for (int idx = threadIdx.x; idx < 1024; idx += 256) en_s[idx] = ep[idx];
        __syncthreads();
        const float* W = (i < 30) ? cond_w + ((size_t)i * 256 + o) * 256
                                  : end2_w + (size_t)o * 256;
        f32x4 a0 = {0.f,0.f,0.f,0.f}, a1 = a0, a2 = a0, a3 = a0;
        for (int c = 0; c < 256; c += 4) {
            f32x4 wv = *(const f32x4*)(W + c);
            #pragma unroll
            for (int cc = 0; cc < 4; ++cc) {
                float wf = wv[cc];
                a0 += wf * en_s[(c + cc) * 4 + 0];
                a1 += wf * en_s[(c + cc) * 4 + 1];
                a2 += wf * en_s[(c + cc) * 4 + 2];
                a3 += wf * en_s[(c + cc) * 4 + 3];
            }
        }
        float bias = (i < 30) ? 0.f : end2_b[o];
        float* dst = (i < 30) ? cond_all + (((size_t)i * 4 + n) * 256 + o) * 16
                              : cond2 + ((size_t)n * 256 + o) * 16;
        f32x4* d4 = (f32x4*)dst;
        d4[0] = a0 + bias; d4[1] = a1 + bias; d4[2] = a2 + bias; d4[3] = a3 + bias;
        return;
    }
    int idx = blockIdx.x * 256 + threadIdx.x;
    if (idx < 491520) { conv_elem(rw, Ares, idx, 128, 128); return; }
    idx -= 491520;
    if (idx < 983040) { conv_elem(kw, Askp, idx, 256, 128); return; }
    idx -= 983040;
    if (idx < 32768) { conv_elem(s1w, A1, idx, 128, 256); return; }
    idx -= 32768;
    if (idx < 32768) { conv_elem(s2w, A2, idx, 256, 128); return; }
    idx -= 32768;
    if (idx < 65536) { conv_elem(e1w, Ae, idx, 256, 256); return; }
    idx -= 65536;
    {   // dil_w -> per-layer A[256][256]
        int lay = idx >> 16, r = idx & 65535;
        int j = r & 7, lane = (r >> 3) & 63, rest = r >> 9;
        int kb = rest & 7, mt = rest >> 3;
        int m = mt * 16 + (lane & 15);
        int k = kb * 32 + ((lane >> 4) << 3) + j;
        float v = (k < 128) ? dwt[(((size_t)lay * 256 + m) * 128 + k) * 2]
                            : dwt[(((size_t)lay * 256 + m) * 128 + (k - 128)) * 2 + 1];
        Adil[(size_t)lay * 65536 + r] = (bf16_t)v;
    }
}

// ---------------- start: l0 = start1@x ; s0 = start2@l0 (t>=4096) ----------------
__global__ __launch_bounds__(512, 4) void k_start(
    const float* __restrict__ x, bf16_t* __restrict__ la, float* __restrict__ sbuf,
    const bf16_t* __restrict__ A1, const bf16_t* __restrict__ A2, int t_base)
{
    __shared__ __align__(16) bf16_t xt[64 * PX];
    __shared__ __align__(16) bf16_t l0[64 * PL];
    int tid = threadIdx.x;
    int n = blockIdx.y, t0 = t_base + blockIdx.x * 64;
    int lane = tid & 63, w = tid >> 6, i16 = lane & 15, q = lane >> 4;
    f32x4 z = {0.f,0.f,0.f,0.f};
    {
        int t = tid & 63;
        for (int c = tid >> 6; c < 256; c += 8)
            xt[t * PX + c] = (bf16_t)x[((size_t)n * 256 + c) * 8192 + t0 + t];
    }
    __syncthreads();
    f32x4 acc[4] = {z,z,z,z};
    #pragma unroll
    for (int kb = 0; kb < 8; ++kb) {
        int koff = kb * 32 + q * 8;
        bf16x8 bf[4];
        #pragma unroll
        for (int nt = 0; nt < 4; ++nt)
            bf[nt] = *(const bf16x8*)(xt + (nt * 16 + i16) * PX + koff);
        bf16x8 af = *(const bf16x8*)(A1 + (((size_t)w * 8 + kb) * 64 + lane) * 8);
        #pragma unroll
        for (int nt = 0; nt < 4; ++nt) acc[nt] = mfma16(af, bf[nt], acc[nt]);
    }
    #pragma unroll
    for (int nt = 0; nt < 4; ++nt)
        #pragma unroll
        for (int j = 0; j < 4; ++j)
            l0[(nt * 16 + i16) * PL + w * 16 + q * 4 + j] = (bf16_t)acc[nt][j];
    __syncthreads();
    {
        int r = tid >> 4, col = (tid & 15) * 8;
        #pragma unroll
        for (int p = 0; p < 2; ++p) {
            int rr = r + p * 32;
            *(i32x4*)(la + ((size_t)n * 8192 + t0 + rr) * 128 + col) =
                *(const i32x4*)(l0 + rr * PL + col);
        }
    }
    if (t0 >= 4096) {
        f32x4 a2[2][4] = {{z,z,z,z},{z,z,z,z}};
        #pragma unroll
        for (int kb = 0; kb < 4; ++kb) {
            int koff = kb * 32 + q * 8;
            bf16x8 bf[4];
            #pragma unroll
            for (int nt = 0; nt < 4; ++nt)
                bf[nt] = *(const bf16x8*)(l0 + (nt * 16 + i16) * PL + koff);
            #pragma unroll
            for (int mt2 = 0; mt2 < 2; ++mt2) {
                bf16x8 af = *(const bf16x8*)(A2 + ((((size_t)2 * w + mt2) * 4 + kb) * 64 + lane) * 8);
                #pragma unroll
                for (int nt = 0; nt < 4; ++nt) a2[mt2][nt] = mfma16(af, bf[nt], a2[mt2][nt]);
            }
        }
        float* sp = sbuf + (size_t)n * 256 * 4096 + (t0 - 4096);
        #pragma unroll
        for (int mt2 = 0; mt2 < 2; ++mt2)
            #pragma unroll
            for (int nt = 0; nt < 4; ++nt)
                #pragma unroll
                for (int j = 0; j < 4; ++j) {
                    int o = (2 * w + mt2) * 16 + q * 4 + j;
                    sp[(size_t)o * 4096 + nt * 16 + i16] = a2[mt2][nt][j];
                }
    }
}

// ---------------- single layer, TT=32, merged staging for dil<32 ----------------
// USEG=1: stream bf16 gate tile to Gl in MFMA B-FRAGMENT order; skip GEMM deferred to k_skip.
// A-fragments + cond hoisted into registers before the staging barrier so their
// L2 latency overlaps the LDS staging (VGPR cap 128 via __launch_bounds__(512,4)).
template<int USEG>
__global__ __launch_bounds__(512, 4) void k_layer(
    const bf16_t* __restrict__ l_in, bf16_t* __restrict__ l_out,
    float* __restrict__ sbuf, bf16_t* __restrict__ Gl,
    const bf16_t* __restrict__ Ad, const bf16_t* __restrict__ Ar,
    const bf16_t* __restrict__ Ak, const float* __restrict__ condL,
    int dil, int t_base, int do_res)
{
    __shared__ __align__(16) bf16_t smA[64 * PL];   // staging (cur|del or combined)
    __shared__ __align__(16) bf16_t sm2[32 * PL];   // gate
    int tid = threadIdx.x;
    int n = blockIdx.y, t0 = t_base + blockIdx.x * 32;
    int lane = tid & 63, w = tid >> 6, i16 = lane & 15, q = lane >> 4;
    f32x4 z = {0.f,0.f,0.f,0.f};
    const float* cond = condL + (size_t)n * 4096;
    int r = tid >> 4, col = (tid & 15) * 8;
    int c_base = w * 16 + q * 4;
    size_t base = (size_t)n * 8192;

    // ---- hoisted loads: cond (8 f32) + GEMM1 A-fragments (16 x 16B) ----
    float cv_s[4], cv_t[4];
    #pragma unroll
    for (int j = 0; j < 4; ++j) {
        cv_s[j] = cond[(c_base + j) * 16 + i16];
        cv_t[j] = cond[(c_base + j + 128) * 16 + i16];
    }
    const bf16x8* AdF = (const bf16x8*)Ad;
    bf16x8 a_s[8], a_t[8];
    #pragma unroll
    for (int kb = 0; kb < 8; ++kb) {
        a_s[kb] = AdF[((size_t)w * 8 + kb) * 64 + lane];
        a_t[kb] = AdF[((size_t)(w + 8) * 8 + kb) * 64 + lane];
    }

    const bf16_t* curp;
    const bf16_t* delp;
    if (dil < 32) {
        // combined window rows [t0-dil, t0+32): del row r = smA[r], cur row r = smA[r+dil]
        int cnt = (32 + dil) * 16;
        for (int idx = tid; idx < cnt; idx += 512) {
            int rr = idx >> 4, c2 = (idx & 15) * 8;
            *(i32x4*)(smA + rr * PL + c2) =
                *(const i32x4*)(l_in + (base + t0 - dil + rr) * 128 + c2);
        }
        delp = smA; curp = smA + dil * PL;
    } else {
        *(i32x4*)(smA + r * PL + col) =
            *(const i32x4*)(l_in + (base + t0 + r) * 128 + col);
        int gp = t0 - dil + r;
        i32x4 v = {0, 0, 0, 0};
        if (gp >= 0) v = *(const i32x4*)(l_in + (base + gp) * 128 + col);
        *(i32x4*)(smA + (32 + r) * PL + col) = v;
        curp = smA; delp = smA + 32 * PL;
    }
    __syncthreads();

    // GEMM1: d = [W0 W1] @ [l_del; l_cur], M=256 K=256, N=32 (A-frags already in regs)
    f32x4 accs[2] = {z,z}, acct[2] = {z,z};
    #pragma unroll
    for (int kb = 0; kb < 8; ++kb) {
        const bf16_t* bsrc = (kb < 4) ? delp : curp;
        int koff = (kb & 3) * 32 + q * 8;
        bf16x8 bf[2];
        #pragma unroll
        for (int nt = 0; nt < 2; ++nt)
            bf[nt] = *(const bf16x8*)(bsrc + (nt * 16 + i16) * PL + koff);
        #pragma unroll
        for (int nt = 0; nt < 2; ++nt) {
            accs[nt] = mfma16(a_s[kb], bf[nt], accs[nt]);
            acct[nt] = mfma16(a_t[kb], bf[nt], acct[nt]);
        }
    }

    // issue res-GEMM A-fragments now so their latency hides under gate+barrier
    const bf16x8* ArF = (const bf16x8*)Ar;
    bf16x8 ar[4];
    if (do_res) {
        #pragma unroll
        for (int kb = 0; kb < 4; ++kb)
            ar[kb] = ArF[((size_t)w * 4 + kb) * 64 + lane];
    }

    {   // gate in-register -> sm2 (cond already in regs)
        #pragma unroll
        for (int nt = 0; nt < 2; ++nt) {
            bf16x4 g4;
            #pragma unroll
            for (int j = 0; j < 4; ++j) {
                float vlo = accs[nt][j] + cv_s[j];
                float vhi = acct[nt][j] + cv_t[j];
                float sg = 1.0f / (1.0f + __expf(-vlo));
                float th = 1.0f - 2.0f / (1.0f + __expf(2.0f * vhi));
                g4[j] = (bf16_t)(sg * th);
            }
            *(bf16x4*)(sm2 + (nt * 16 + i16) * PL + c_base) = g4;
        }
    }
    __syncthreads();   // gate ready; all GEMM1 LDS reads done

    if (USEG) {
        if (t0 >= 4096) {   // stream gate tile to G in fragment order (coalesced 16B/thread)
            int tt = ((tid & 256) >> 4) + (tid & 15);               // (tid>>8)*16 + i16
            int cc = ((tid >> 6) & 3) * 32 + ((tid >> 4) & 3) * 8;  // kb*32 + qf*8
            bf16x8 gv = *(const bf16x8*)(sm2 + tt * PL + cc);
            *(bf16x8*)(Gl + ((size_t)n * 4096 + (t0 - 4096)) * 128 + tid * 8) = gv;
        }
    }

    f32x4 acc2[2] = {z,z};
    if (do_res || !USEG) {
        int do_skip = (!USEG) && (t0 >= 4096);
        f32x4 acc3[2][2] = {{z,z},{z,z}};
        const bf16x8* AkF = (const bf16x8*)Ak;
        #pragma unroll
        for (int kb = 0; kb < 4; ++kb) {
            int koff = kb * 32 + q * 8;
            bf16x8 bf[2];
            #pragma unroll
            for (int nt = 0; nt < 2; ++nt)
                bf[nt] = *(const bf16x8*)(sm2 + (nt * 16 + i16) * PL + koff);
            if (do_res) {
                #pragma unroll
                for (int nt = 0; nt < 2; ++nt) acc2[nt] = mfma16(ar[kb], bf[nt], acc2[nt]);
            }
            if (do_skip) {
                #pragma unroll
                for (int mt2 = 0; mt2 < 2; ++mt2) {
                    bf16x8 ak = AkF[((size_t)(2 * w + mt2) * 4 + kb) * 64 + lane];
                    #pragma unroll
                    for (int nt = 0; nt < 2; ++nt)
                        acc3[mt2][nt] = mfma16(ak, bf[nt], acc3[mt2][nt]);
                }
            }
        }
        if (do_skip) {
            float* sp = sbuf + (size_t)n * 256 * 4096 + (t0 - 4096);
            #pragma unroll
            for (int mt2 = 0; mt2 < 2; ++mt2)
                #pragma unroll
                for (int nt = 0; nt < 2; ++nt)
                    #pragma unroll
                    for (int j = 0; j < 4; ++j) {
                        int o = (2 * w + mt2) * 16 + q * 4 + j;
                        sp[(size_t)o * 4096 + nt * 16 + i16] += acc3[mt2][nt][j];
                    }
        }
    }

    if (do_res) {
        // sum = f32(l_cur) + res in regs; direct 8B store (no LDS roundtrip, no extra barriers)
        #pragma unroll
        for (int nt = 0; nt < 2; ++nt) {
            int trow = (nt * 16 + i16) * PL;
            bf16x4 lv = *(const bf16x4*)(curp + trow + c_base);
            bf16x4 o4;
            #pragma unroll
            for (int j = 0; j < 4; ++j)
                o4[j] = (bf16_t)((float)lv[j] + acc2[nt][j]);
            *(bf16x4*)(l_out + (base + t0 + nt * 16 + i16) * 128 + c_base) = o4;
        }
    }
}

// ---------------- deferred skip mega-GEMM: s += sum_i skip_i @ g_i ----------------
// TT=64, fragment-order G. Named-register (static) pipelines:
//   * Askp fragments double-buffered (akA/akB), prefetched 1 layer ahead
//   * G tile regs double-buffered (gA/gB), prefetched 2 layers ahead
// Raw s_barrier + lgkmcnt(0) only (no vmcnt drain). __launch_bounds__(512,2):
// 1 block/CU (grid=256) so VGPR cap 256 costs no occupancy.
#define SKIP_HALF(I, AKU, AKP, GW0, GW1)                                        \
    {                                                                           \
        const int i_ = (I);                                                     \
        if (i_ + 1 < 30) {                                                      \
            bf16_t* db = gbuf[(i_ + 1) & 1];                                    \
            *(i32x4*)(db + tid * 8) = GW0;                                      \
            *(i32x4*)(db + 4096 + tid * 8) = GW1;                               \
        }                                                                       \
        if (i_ + 3 < 30) {                                                      \
            const bf16_t* srcp = gb + (size_t)(i_ + 3) * GLS;                   \
            GW0 = *(const i32x4*)(srcp);                                        \
            GW1 = *(const i32x4*)(srcp + 4096);                                 \
        }                                                                       \
        if (i_ + 1 < 30) {                                                      \
            const bf16x8* An = (const bf16x8*)(Askp + (size_t)(i_ + 1) * 32768);\
            _Pragma("unroll")                                                   \
            for (int kb = 0; kb < 4; ++kb) {                                    \
                AKP[2 * kb]     = An[fi0 + kb * 64];                            \
                AKP[2 * kb + 1] = An[fi1 + kb * 64];                            \
            }                                                                   \
        }                                                                       \
        const bf16_t* gp_ = gbuf[i_ & 1];                                       \
        _Pragma("unroll")                                                       \
        for (int kb = 0; kb < 4; ++kb) {                                        \
            _Pragma("unroll")                                                   \
            for (int nt = 0; nt < 4; ++nt) {                                    \
                bf16x8 bfv = *(const bf16x8*)(gp_ + (nt >> 1) * 4096 +          \
                              (((nt & 1) * 4 + kb) * 64 + lane) * 8);           \
                acc[0][nt] = mfma16(AKU[2 * kb], bfv, acc[0][nt]);              \
                acc[1][nt] = mfma16(AKU[2 * kb + 1], bfv, acc[1][nt]);          \
            }                                                                   \
        }                                                                       \
        if (i_ + 1 < 30) {                                                      \
            asm volatile("s_waitcnt lgkmcnt(0)" ::: "memory");                  \
            __builtin_amdgcn_sched_barrier(0);                                  \
            __builtin_amdgcn_s_barrier();                                       \
            __builtin_amdgcn_sched_barrier(0);                                  \
        }                                                                       \
    }

__global__ __launch_bounds__(512, 2) void k_skip(
    const bf16_t* __restrict__ G, float* __restrict__ sbuf,
    const bf16_t* __restrict__ Askp)
{
    __shared__ __align__(16) bf16_t gbuf[2][8192];
    int tid = threadIdx.x;
    int n = blockIdx.y, t0 = blockIdx.x * 64;
    int lane = tid & 63, w = tid >> 6, i16 = lane & 15, q = lane >> 4;
    f32x4 z = {0.f,0.f,0.f,0.f};
    f32x4 acc[2][4] = {{z,z,z,z},{z,z,z,z}};
    const size_t GLS = (size_t)4 * 4096 * 128;   // per-layer stride in G (elems)
    const bf16_t* gb = G + ((size_t)n * 4096 + t0) * 128 + tid * 8;
    int fi0 = (2 * w) * 256 + lane;       // fragment row base for out-row pair 2w
    int fi1 = fi0 + 256;                  // 2w+1
    // Askp fragment regs (layer parity: akA=even layers, akB=odd)
    bf16x8 akA[8], akB[8];
    {
        const bf16x8* A0 = (const bf16x8*)Askp;
        #pragma unroll
        for (int kb = 0; kb < 4; ++kb) {
            akA[2 * kb]     = A0[fi0 + kb * 64];
            akA[2 * kb + 1] = A0[fi1 + kb * 64];
        }
    }
    // G regs: gA written at even iters (odd layers), gB at odd iters (even layers)
    i32x4 gA0, gA1, gB0, gB1;
    {
        i32x4 t0v = *(const i32x4*)(gb);
        i32x4 t1v = *(const i32x4*)(gb + 4096);
        *(i32x4*)(gbuf[0] + tid * 8) = t0v;
        *(i32x4*)(gbuf[0] + 4096 + tid * 8) = t1v;
    }
    gA0 = *(const i32x4*)(gb + 1 * GLS);
    gA1 = *(const i32x4*)(gb + 1 * GLS + 4096);
    gB0 = *(const i32x4*)(gb + 2 * GLS);
    gB1 = *(const i32x4*)(gb + 2 * GLS + 4096);
    __syncthreads();   // prologue: single full drain
    #pragma unroll 1
    for (int ii = 0; ii < 30; ii += 2) {
        SKIP_HALF(ii,     akA, akB, gA0, gA1)
        SKIP_HALF(ii + 1, akB, akA, gB0, gB1)
    }
    float* sp = sbuf + (size_t)n * 256 * 4096 + t0;
    #pragma unroll
    for (int mt2 = 0; mt2 < 2; ++mt2)
        #pragma unroll
        for (int nt = 0; nt < 4; ++nt)
            #pragma unroll
            for (int j = 0; j < 4; ++j) {
                int o = (2 * w + mt2) * 16 + q * 4 + j;
                sp[(size_t)o * 4096 + nt * 16 + i16] += acc[mt2][nt][j];
            }
}

// ---------------- end: out = relu(end1@relu(s) + b1 + cond2_tiled) ----------------
__global__ __launch_bounds__(512) void k_end(
    const float* __restrict__ sbuf, float* __restrict__ out,
    const bf16_t* __restrict__ Ae, const float* __restrict__ cond2,
    const float* __restrict__ b1)
{
    __shared__ __align__(16) bf16_t st[64 * PX];
    __shared__ float c2[4096];
    __shared__ float b1s[256];
    int tid = threadIdx.x;
    int n = blockIdx.y, t0 = blockIdx.x * 64;
    int lane = tid & 63, w = tid >> 6, i16 = lane & 15, q = lane >> 4;
    f32x4 z = {0.f,0.f,0.f,0.f};
    {
        int t = tid & 63;
        for (int c = tid >> 6; c < 256; c += 8) {
            float v = sbuf[((size_t)n * 256 + c) * 4096 + t0 + t];
            st[t * PX + c] = (bf16_t)fmaxf(v, 0.f);
        }
        const f32x4* cc = (const f32x4*)(cond2 + (size_t)n * 4096);
        for (int idx = tid; idx < 1024; idx += 512) ((f32x4*)c2)[idx] = cc[idx];
        if (tid < 64) ((f32x4*)b1s)[tid] = ((const f32x4*)b1)[tid];
    }
    __syncthreads();
    f32x4 acc[2][4] = {{z,z,z,z},{z,z,z,z}};
    #pragma unroll
    for (int kb = 0; kb < 8; ++kb) {
        int koff = kb * 32 + q * 8;
        bf16x8 bf[4];
        #pragma unroll
        for (int nt = 0; nt < 4; ++nt)
            bf[nt] = *(const bf16x8*)(st + (nt * 16 + i16) * PX + koff);
        #pragma unroll
        for (int mt2 = 0; mt2 < 2; ++mt2) {
            bf16x8 af = *(const bf16x8*)(Ae + ((((size_t)2 * w + mt2) * 8 + kb) * 64 + lane) * 8);
            #pragma unroll
            for (int nt = 0; nt < 4; ++nt) acc[mt2][nt] = mfma16(af, bf[nt], acc[mt2][nt]);
        }
    }
    #pragma unroll
    for (int mt2 = 0; mt2 < 2; ++mt2)
        #pragma unroll
        for (int j = 0; j < 4; ++j) {
            int o = (2 * w + mt2) * 16 + q * 4 + j;
            float bb = b1s[o] + c2[o * 16 + i16];
            #pragma unroll
            for (int nt = 0; nt < 4; ++nt) {
                float v = acc[mt2][nt][j] + bb;
                out[((size_t)n * 256 + o) * 4096 + t0 + nt * 16 + i16] = fmaxf(v, 0.f);
            }
        }
}

extern "C" void kernel_launch(void* const* d_in, const int* in_sizes, int n_in,
                              void* d_out, int out_size, void* d_ws, size_t ws_size,
                              hipStream_t stream) {
    const float* x   = (const float*)d_in[0];
    const float* en  = (const float*)d_in[1];
    const float* s1w = (const float*)d_in[2];
    const float* s2w = (const float*)d_in[3];
    const float* cw  = (const float*)d_in[4];
    const float* dw  = (const float*)d_in[5];
    const float* rw  = (const float*)d_in[6];
    const float* kw  = (const float*)d_in[7];
    const float* e1w = (const float*)d_in[8];
    const float* e1b = (const float*)d_in[9];
    const float* e2w = (const float*)d_in[10];
    const float* e2b = (const float*)d_in[11];
    float* out = (float*)d_out;

    char* p = (char*)d_ws;
    auto take = [&](size_t bytes) {
        char* r = p;
        p += (bytes + 255) & ~(size_t)255;
        return r;
    };
    bf16_t* A1   = (bf16_t*)take((size_t)128 * 256 * 2);
    bf16_t* A2   = (bf16_t*)take((size_t)256 * 128 * 2);
    bf16_t* Ae   = (bf16_t*)take((size_t)256 * 256 * 2);
    bf16_t* Adil = (bf16_t*)take((size_t)30 * 65536 * 2);
    bf16_t* Ares = (bf16_t*)take((size_t)30 * 16384 * 2);
    bf16_t* Askp = (bf16_t*)take((size_t)30 * 32768 * 2);
    float*  condA= (float*)take((size_t)30 * 16384 * 4);
    float*  cond2= (float*)take((size_t)16384 * 4);
    bf16_t* la   = (bf16_t*)take((size_t)4 * 8192 * 128 * 2);
    bf16_t* lb   = (bf16_t*)take((size_t)4 * 8192 * 128 * 2);
    float*  sbuf = (float*)take((size_t)4 * 256 * 4096 * 4);
    bf16_t* G    = (bf16_t*)take((size_t)30 * 4 * 4096 * 128 * 2);  // last
    bool useG = ((size_t)(p - (char*)d_ws) <= ws_size);

    k_prep<<<14076, 256, 0, stream>>>(rw, kw, s1w, s2w, e1w, dw,
                                      cw, e2w, e2b, en,
                                      Ares, Askp, A1, A2, Ae, Adil, condA, cond2);

    // causal trim table (host)
    int a[30];
    a[29] = 4096;
    for (int i = 28; i >= 0; --i) {
        int nx = a[i + 1] - (1 << ((i + 1) % 10));
        a[i] = nx < 4096 ? (nx & ~63) : 4096;
    }

    k_start<<<dim3(127, 4), 512, 0, stream>>>(x, la, sbuf, A1, A2, 64);

    bf16_t* src = la;
    bf16_t* dst = lb;
    for (int i = 0; i < 30; ++i) {
        dim3 grid((8192 - a[i]) / 32, 4);
        if (useG)
            k_layer<1><<<grid, 512, 0, stream>>>(src, dst, sbuf,
                G + (size_t)i * 4 * 4096 * 128,
                Adil + (size_t)i * 65536, Ares + (size_t)i * 16384,
                Askp + (size_t)i * 32768, condA + (size_t)i * 16384,
                1 << (i % 10), a[i], i < 29 ? 1 : 0);
        else
            k_layer<0><<<grid, 512, 0, stream>>>(src, dst, sbuf, (bf16_t*)nullptr,
                Adil + (size_t)i * 65536, Ares + (size_t)i * 16384,
                Askp + (size_t)i * 32768, condA + (size_t)i * 16384,
                1 << (i % 10), a[i], i < 29 ? 1 : 0);
        bf16_t* t = src; src = dst; dst = t;
    }
    if (useG)
        k_skip<<<dim3(64, 4), 512, 0, stream>>>(G, sbuf, Askp);
    k_end<<<dim3(64, 4), 512, 0, stream>>>(sbuf, out, Ae, cond2, e1b);
}

// Round 3
// 626.607 us; speedup vs baseline: 1.0330x; 1.0196x over previous
//
#include <hip/hip_runtime.h>

typedef __bf16 bf16_t;
typedef __bf16 bf16x8 __attribute__((ext_vector_type(8)));
typedef __bf16 bf16x4 __attribute__((ext_vector_type(4)));
typedef float  f32x4  __attribute__((ext_vector_type(4)));
typedef int    i32x4  __attribute__((ext_vector_type(4)));

#define PL 136   // padded row stride (elems) for [t][128] bf16 tiles (272B = 16B-aligned)
#define PX 264   // padded row stride (elems) for [t][256] bf16 tiles

__device__ __forceinline__ f32x4 mfma16(bf16x8 a, bf16x8 b, f32x4 c) {
    return __builtin_amdgcn_mfma_f32_16x16x32_bf16(a, b, c, 0, 0, 0);
}

// ---------------- merged prep: weight conversion + conditioning ----------------
// 8 elems/thread: dst fragment order makes j=0..7 consecutive in src, so each
// thread does 2 coalesced f32x4 loads + 1 bf16x8 store (wave = 16 rows x 128B).
__device__ __forceinline__ void conv8(const float* __restrict__ src,
                                      bf16_t* __restrict__ dst,
                                      int g, int M, int K) {
    int MK8 = (M * K) >> 3;
    int lay = g / MK8;
    int r = g - lay * MK8;
    int lane = r & 63, rest = r >> 6;
    int KB = K >> 5;
    int kb = rest % KB, mt = rest / KB;
    int m = mt * 16 + (lane & 15);
    int k = kb * 32 + ((lane >> 4) << 3);
    const float* s = src + (size_t)lay * M * K + (size_t)m * K + k;
    f32x4 v0 = *(const f32x4*)s;
    f32x4 v1 = *(const f32x4*)(s + 4);
    bf16x8 o;
    o[0] = (bf16_t)v0[0]; o[1] = (bf16_t)v0[1]; o[2] = (bf16_t)v0[2]; o[3] = (bf16_t)v0[3];
    o[4] = (bf16_t)v1[0]; o[5] = (bf16_t)v1[1]; o[6] = (bf16_t)v1[2]; o[7] = (bf16_t)v1[3];
    *(bf16x8*)(dst + (size_t)g * 8) = o;
}

__global__ __launch_bounds__(256) void k_prep(
                       const float* __restrict__ rw, const float* __restrict__ kw,
                       const float* __restrict__ s1w, const float* __restrict__ s2w,
                       const float* __restrict__ e1w, const float* __restrict__ dwt,
                       const float* __restrict__ cond_w, const float* __restrict__ end2_w,
                       const float* __restrict__ end2_b, const float* __restrict__ en,
                       bf16_t* __restrict__ Ares, bf16_t* __restrict__ Askp,
                       bf16_t* __restrict__ A1, bf16_t* __restrict__ A2,
                       bf16_t* __restrict__ Ae, bf16_t* __restrict__ Adil,
                       float* __restrict__ cond_all, float* __restrict__ cond2) {
    if (blockIdx.x >= 1744) {
        // cond: out[o,e] = sum_c W_i[o,c]*en[n,c,e]. Block = (i, n, 64-o-chunk);
        // 4 threads/o each own a 64-wide c-slice (vectorized W reads), LDS reduce.
        __shared__ f32x4 en_s[1024];
        __shared__ f32x4 red[1024];
        int bi = blockIdx.x - 1744;
        int i = bi >> 4;            // 0..30
        int n = (bi >> 2) & 3;
        int og = bi & 3;
        int tid = threadIdx.x;
        const f32x4* ep = (const f32x4*)(en + (size_t)n * 4096);
        for (int idx = tid; idx < 1024; idx += 256) en_s[idx] = ep[idx];
        __syncthreads();
        int o_loc = tid >> 2, part = tid & 3;
        int o = og * 64 + o_loc;
        const float* W = (i < 30) ? cond_w + ((size_t)i * 256 + o) * 256
                                  : end2_w + (size_t)o * 256;
        const float* Wp = W + part * 64;
        f32x4 a0 = {0.f,0.f,0.f,0.f}, a1 = a0, a2 = a0, a3 = a0;
        for (int c = 0; c < 64; c += 4) {
            f32x4 wv = *(const f32x4*)(Wp + c);
            int cg = part * 64 + c;
            #pragma unroll
            for (int cc = 0; cc < 4; ++cc) {
                float wf = wv[cc];
                a0 += wf * en_s[(cg + cc) * 4 + 0];
                a1 += wf * en_s[(cg + cc) * 4 + 1];
                a2 += wf * en_s[(cg + cc) * 4 + 2];
                a3 += wf * en_s[(cg + cc) * 4 + 3];
            }
        }
        red[tid * 4 + 0] = a0; red[tid * 4 + 1] = a1;
        red[tid * 4 + 2] = a2; red[tid * 4 + 3] = a3;
        __syncthreads();
        if (tid < 64) {
            int o2 = og * 64 + tid;
            float bias = (i < 30) ? 0.f : end2_b[o2];
            float* dst = (i < 30) ? cond_all + (((size_t)i * 4 + n) * 256 + o2) * 16
                                  : cond2 + ((size_t)n * 256 + o2) * 16;
            f32x4* d4 = (f32x4*)dst;
            #pragma unroll
            for (int t = 0; t < 4; ++t) {
                f32x4 s = red[(tid * 4 + 0) * 4 + t] + red[(tid * 4 + 1) * 4 + t]
                        + red[(tid * 4 + 2) * 4 + t] + red[(tid * 4 + 3) * 4 + t];
                d4[t] = s + bias;
            }
        }
        return;
    }
    int g = blockIdx.x * 256 + threadIdx.x;
    if (g < 61440) { conv8(rw, Ares, g, 128, 128); return; }
    g -= 61440;
    if (g < 122880) { conv8(kw, Askp, g, 256, 128); return; }
    g -= 122880;
    if (g < 4096) { conv8(s1w, A1, g, 128, 256); return; }
    g -= 4096;
    if (g < 4096) { conv8(s2w, A2, g, 256, 128); return; }
    g -= 4096;
    if (g < 8192) { conv8(e1w, Ae, g, 256, 256); return; }
    g -= 8192;
    {   // dil_w -> per-layer A[256][256], 8 elems/thread (64B span, stride-2 pick)
        int lay = g >> 13, r = g & 8191;
        int lane = r & 63, rest = r >> 6;
        int kb = rest & 7, mt = rest >> 3;
        int m = mt * 16 + (lane & 15);
        int k0 = kb * 32 + ((lane >> 4) << 3);
        int sel = (k0 < 128) ? 0 : 1;
        int kk = (k0 < 128) ? k0 : k0 - 128;
        const float* s = dwt + (((size_t)lay * 256 + m) * 128 + kk) * 2;
        f32x4 c0 = *(const f32x4*)(s);
        f32x4 c1 = *(const f32x4*)(s + 4);
        f32x4 c2 = *(const f32x4*)(s + 8);
        f32x4 c3 = *(const f32x4*)(s + 12);
        bf16x8 o;
        o[0] = (bf16_t)c0[sel];     o[1] = (bf16_t)c0[2 + sel];
        o[2] = (bf16_t)c1[sel];     o[3] = (bf16_t)c1[2 + sel];
        o[4] = (bf16_t)c2[sel];     o[5] = (bf16_t)c2[2 + sel];
        o[6] = (bf16_t)c3[sel];     o[7] = (bf16_t)c3[2 + sel];
        *(bf16x8*)(Adil + (size_t)lay * 65536 + (size_t)r * 8) = o;
    }
}

// ---------------- start: l0 = start1@x ; s0 = start2@l0 (t>=4096) ----------------
__global__ __launch_bounds__(512, 4) void k_start(
    const float* __restrict__ x, bf16_t* __restrict__ la, float* __restrict__ sbuf,
    const bf16_t* __restrict__ A1, const bf16_t* __restrict__ A2, int t_base)
{
    __shared__ __align__(16) bf16_t xt[64 * PX];
    __shared__ __align__(16) bf16_t l0[64 * PL];
    int tid = threadIdx.x;
    int n = blockIdx.y, t0 = t_base + blockIdx.x * 64;
    int lane = tid & 63, w = tid >> 6, i16 = lane & 15, q = lane >> 4;
    f32x4 z = {0.f,0.f,0.f,0.f};
    {
        int t = tid & 63;
        for (int c = tid >> 6; c < 256; c += 8)
            xt[t * PX + c] = (bf16_t)x[((size_t)n * 256 + c) * 8192 + t0 + t];
    }
    __syncthreads();
    f32x4 acc[4] = {z,z,z,z};
    #pragma unroll
    for (int kb = 0; kb < 8; ++kb) {
        int koff = kb * 32 + q * 8;
        bf16x8 bf[4];
        #pragma unroll
        for (int nt = 0; nt < 4; ++nt)
            bf[nt] = *(const bf16x8*)(xt + (nt * 16 + i16) * PX + koff);
        bf16x8 af = *(const bf16x8*)(A1 + (((size_t)w * 8 + kb) * 64 + lane) * 8);
        #pragma unroll
        for (int nt = 0; nt < 4; ++nt) acc[nt] = mfma16(af, bf[nt], acc[nt]);
    }
    #pragma unroll
    for (int nt = 0; nt < 4; ++nt)
        #pragma unroll
        for (int j = 0; j < 4; ++j)
            l0[(nt * 16 + i16) * PL + w * 16 + q * 4 + j] = (bf16_t)acc[nt][j];
    __syncthreads();
    {
        int r = tid >> 4, col = (tid & 15) * 8;
        #pragma unroll
        for (int p = 0; p < 2; ++p) {
            int rr = r + p * 32;
            *(i32x4*)(la + ((size_t)n * 8192 + t0 + rr) * 128 + col) =
                *(const i32x4*)(l0 + rr * PL + col);
        }
    }
    if (t0 >= 4096) {
        f32x4 a2[2][4] = {{z,z,z,z},{z,z,z,z}};
        #pragma unroll
        for (int kb = 0; kb < 4; ++kb) {
            int koff = kb * 32 + q * 8;
            bf16x8 bf[4];
            #pragma unroll
            for (int nt = 0; nt < 4; ++nt)
                bf[nt] = *(const bf16x8*)(l0 + (nt * 16 + i16) * PL + koff);
            #pragma unroll
            for (int mt2 = 0; mt2 < 2; ++mt2) {
                bf16x8 af = *(const bf16x8*)(A2 + ((((size_t)2 * w + mt2) * 4 + kb) * 64 + lane) * 8);
                #pragma unroll
                for (int nt = 0; nt < 4; ++nt) a2[mt2][nt] = mfma16(af, bf[nt], a2[mt2][nt]);
            }
        }
        float* sp = sbuf + (size_t)n * 256 * 4096 + (t0 - 4096);
        #pragma unroll
        for (int mt2 = 0; mt2 < 2; ++mt2)
            #pragma unroll
            for (int nt = 0; nt < 4; ++nt)
                #pragma unroll
                for (int j = 0; j < 4; ++j) {
                    int o = (2 * w + mt2) * 16 + q * 4 + j;
                    sp[(size_t)o * 4096 + nt * 16 + i16] = a2[mt2][nt][j];
                }
    }
}

// ---------------- single layer, TT=32, merged staging for dil<32 ----------------
// USEG=1: stream bf16 gate tile to Gl in MFMA B-FRAGMENT order; skip GEMM deferred to k_skip.
// A-fragments + cond hoisted into registers before the staging barrier so their
// L2 latency overlaps the LDS staging (VGPR cap 128 via __launch_bounds__(512,4)).
template<int USEG>
__global__ __launch_bounds__(512, 4) void k_layer(
    const bf16_t* __restrict__ l_in, bf16_t* __restrict__ l_out,
    float* __restrict__ sbuf, bf16_t* __restrict__ Gl,
    const bf16_t* __restrict__ Ad, const bf16_t* __restrict__ Ar,
    const bf16_t* __restrict__ Ak, const float* __restrict__ condL,
    int dil, int t_base, int do_res)
{
    __shared__ __align__(16) bf16_t smA[64 * PL];   // staging (cur|del or combined)
    __shared__ __align__(16) bf16_t sm2[32 * PL];   // gate
    int tid = threadIdx.x;
    int n = blockIdx.y, t0 = t_base + blockIdx.x * 32;
    int lane = tid & 63, w = tid >> 6, i16 = lane & 15, q = lane >> 4;
    f32x4 z = {0.f,0.f,0.f,0.f};
    const float* cond = condL + (size_t)n * 4096;
    int r = tid >> 4, col = (tid & 15) * 8;
    int c_base = w * 16 + q * 4;
    size_t base = (size_t)n * 8192;

    // ---- hoisted loads: cond (8 f32) + GEMM1 A-fragments (16 x 16B) ----
    float cv_s[4], cv_t[4];
    #pragma unroll
    for (int j = 0; j < 4; ++j) {
        cv_s[j] = cond[(c_base + j) * 16 + i16];
        cv_t[j] = cond[(c_base + j + 128) * 16 + i16];
    }
    const bf16x8* AdF = (const bf16x8*)Ad;
    bf16x8 a_s[8], a_t[8];
    #pragma unroll
    for (int kb = 0; kb < 8; ++kb) {
        a_s[kb] = AdF[((size_t)w * 8 + kb) * 64 + lane];
        a_t[kb] = AdF[((size_t)(w + 8) * 8 + kb) * 64 + lane];
    }

    const bf16_t* curp;
    const bf16_t* delp;
    if (dil < 32) {
        // combined window rows [t0-dil, t0+32): del row r = smA[r], cur row r = smA[r+dil]
        int cnt = (32 + dil) * 16;
        for (int idx = tid; idx < cnt; idx += 512) {
            int rr = idx >> 4, c2 = (idx & 15) * 8;
            *(i32x4*)(smA + rr * PL + c2) =
                *(const i32x4*)(l_in + (base + t0 - dil + rr) * 128 + c2);
        }
        delp = smA; curp = smA + dil * PL;
    } else {
        *(i32x4*)(smA + r * PL + col) =
            *(const i32x4*)(l_in + (base + t0 + r) * 128 + col);
        int gp = t0 - dil + r;
        i32x4 v = {0, 0, 0, 0};
        if (gp >= 0) v = *(const i32x4*)(l_in + (base + gp) * 128 + col);
        *(i32x4*)(smA + (32 + r) * PL + col) = v;
        curp = smA; delp = smA + 32 * PL;
    }
    __syncthreads();

    // GEMM1: d = [W0 W1] @ [l_del; l_cur], M=256 K=256, N=32 (A-frags already in regs)
    f32x4 accs[2] = {z,z}, acct[2] = {z,z};
    #pragma unroll
    for (int kb = 0; kb < 8; ++kb) {
        const bf16_t* bsrc = (kb < 4) ? delp : curp;
        int koff = (kb & 3) * 32 + q * 8;
        bf16x8 bf[2];
        #pragma unroll
        for (int nt = 0; nt < 2; ++nt)
            bf[nt] = *(const bf16x8*)(bsrc + (nt * 16 + i16) * PL + koff);
        #pragma unroll
        for (int nt = 0; nt < 2; ++nt) {
            accs[nt] = mfma16(a_s[kb], bf[nt], accs[nt]);
            acct[nt] = mfma16(a_t[kb], bf[nt], acct[nt]);
        }
    }

    // issue res-GEMM A-fragments now so their latency hides under gate+barrier
    const bf16x8* ArF = (const bf16x8*)Ar;
    bf16x8 ar[4];
    if (do_res) {
        #pragma unroll
        for (int kb = 0; kb < 4; ++kb)
            ar[kb] = ArF[((size_t)w * 4 + kb) * 64 + lane];
    }

    {   // gate in-register -> sm2 (cond already in regs)
        #pragma unroll
        for (int nt = 0; nt < 2; ++nt) {
            bf16x4 g4;
            #pragma unroll
            for (int j = 0; j < 4; ++j) {
                float vlo = accs[nt][j] + cv_s[j];
                float vhi = acct[nt][j] + cv_t[j];
                float sg = 1.0f / (1.0f + __expf(-vlo));
                float th = 1.0f - 2.0f / (1.0f + __expf(2.0f * vhi));
                g4[j] = (bf16_t)(sg * th);
            }
            *(bf16x4*)(sm2 + (nt * 16 + i16) * PL + c_base) = g4;
        }
    }
    __syncthreads();   // gate ready; all GEMM1 LDS reads done

    if (USEG) {
        if (t0 >= 4096) {   // stream gate tile to G in fragment order (coalesced 16B/thread)
            int tt = ((tid & 256) >> 4) + (tid & 15);               // (tid>>8)*16 + i16
            int cc = ((tid >> 6) & 3) * 32 + ((tid >> 4) & 3) * 8;  // kb*32 + qf*8
            bf16x8 gv = *(const bf16x8*)(sm2 + tt * PL + cc);
            *(bf16x8*)(Gl + ((size_t)n * 4096 + (t0 - 4096)) * 128 + tid * 8) = gv;
        }
    }

    f32x4 acc2[2] = {z,z};
    if (do_res || !USEG) {
        int do_skip = (!USEG) && (t0 >= 4096);
        f32x4 acc3[2][2] = {{z,z},{z,z}};
        const bf16x8* AkF = (const bf16x8*)Ak;
        #pragma unroll
        for (int kb = 0; kb < 4; ++kb) {
            int koff = kb * 32 + q * 8;
            bf16x8 bf[2];
            #pragma unroll
            for (int nt = 0; nt < 2; ++nt)
                bf[nt] = *(const bf16x8*)(sm2 + (nt * 16 + i16) * PL + koff);
            if (do_res) {
                #pragma unroll
                for (int nt = 0; nt < 2; ++nt) acc2[nt] = mfma16(ar[kb], bf[nt], acc2[nt]);
            }
            if (do_skip) {
                #pragma unroll
                for (int mt2 = 0; mt2 < 2; ++mt2) {
                    bf16x8 ak = AkF[((size_t)(2 * w + mt2) * 4 + kb) * 64 + lane];
                    #pragma unroll
                    for (int nt = 0; nt < 2; ++nt)
                        acc3[mt2][nt] = mfma16(ak, bf[nt], acc3[mt2][nt]);
                }
            }
        }
        if (do_skip) {
            float* sp = sbuf + (size_t)n * 256 * 4096 + (t0 - 4096);
            #pragma unroll
            for (int mt2 = 0; mt2 < 2; ++mt2)
                #pragma unroll
                for (int nt = 0; nt < 2; ++nt)
                    #pragma unroll
                    for (int j = 0; j < 4; ++j) {
                        int o = (2 * w + mt2) * 16 + q * 4 + j;
                        sp[(size_t)o * 4096 + nt * 16 + i16] += acc3[mt2][nt][j];
                    }
        }
    }

    if (do_res) {
        // sum = f32(l_cur) + res in regs; direct 8B store (no LDS roundtrip, no extra barriers)
        #pragma unroll
        for (int nt = 0; nt < 2; ++nt) {
            int trow = (nt * 16 + i16) * PL;
            bf16x4 lv = *(const bf16x4*)(curp + trow + c_base);
            bf16x4 o4;
            #pragma unroll
            for (int j = 0; j < 4; ++j)
                o4[j] = (bf16_t)((float)lv[j] + acc2[nt][j]);
            *(bf16x4*)(l_out + (base + t0 + nt * 16 + i16) * 128 + c_base) = o4;
        }
    }
}

// ---------------- deferred skip mega-GEMM: s += sum_i skip_i @ g_i ----------------
// TT=64, fragment-order G. Named-register (static) pipelines:
//   * Askp fragments double-buffered (akA/akB), prefetched 1 layer ahead
//   * G tile regs double-buffered (gA/gB), prefetched 2 layers ahead
// Raw s_barrier + lgkmcnt(0) only (no vmcnt drain). __launch_bounds__(512,2):
// 1 block/CU (grid=256) so VGPR cap 256 costs no occupancy.
#define SKIP_HALF(I, AKU, AKP, GW0, GW1)                                        \
    {                                                                           \
        const int i_ = (I);                                                     \
        if (i_ + 1 < 30) {                                                      \
            bf16_t* db = gbuf[(i_ + 1) & 1];                                    \
            *(i32x4*)(db + tid * 8) = GW0;                                      \
            *(i32x4*)(db + 4096 + tid * 8) = GW1;                               \
        }                                                                       \
        if (i_ + 3 < 30) {                                                      \
            const bf16_t* srcp = gb + (size_t)(i_ + 3) * GLS;                   \
            GW0 = *(const i32x4*)(srcp);                                        \
            GW1 = *(const i32x4*)(srcp + 4096);                                 \
        }                                                                       \
        if (i_ + 1 < 30) {                                                      \
            const bf16x8* An = (const bf16x8*)(Askp + (size_t)(i_ + 1) * 32768);\
            _Pragma("unroll")                                                   \
            for (int kb = 0; kb < 4; ++kb) {                                    \
                AKP[2 * kb]     = An[fi0 + kb * 64];                            \
                AKP[2 * kb + 1] = An[fi1 + kb * 64];                            \
            }                                                                   \
        }                                                                       \
        const bf16_t* gp_ = gbuf[i_ & 1];                                       \
        _Pragma("unroll")                                                       \
        for (int kb = 0; kb < 4; ++kb) {                                        \
            _Pragma("unroll")                                                   \
            for (int nt = 0; nt < 4; ++nt) {                                    \
                bf16x8 bfv = *(const bf16x8*)(gp_ + (nt >> 1) * 4096 +          \
                              (((nt & 1) * 4 + kb) * 64 + lane) * 8);           \
                acc[0][nt] = mfma16(AKU[2 * kb], bfv, acc[0][nt]);              \
                acc[1][nt] = mfma16(AKU[2 * kb + 1], bfv, acc[1][nt]);          \
            }                                                                   \
        }                                                                       \
        if (i_ + 1 < 30) {                                                      \
            asm volatile("s_waitcnt lgkmcnt(0)" ::: "memory");                  \
            __builtin_amdgcn_sched_barrier(0);                                  \
            __builtin_amdgcn_s_barrier();                                       \
            __builtin_amdgcn_sched_barrier(0);                                  \
        }                                                                       \
    }

__global__ __launch_bounds__(512, 2) void k_skip(
    const bf16_t* __restrict__ G, float* __restrict__ sbuf,
    const bf16_t* __restrict__ Askp)
{
    __shared__ __align__(16) bf16_t gbuf[2][8192];
    int tid = threadIdx.x;
    int n = blockIdx.y, t0 = blockIdx.x * 64;
    int lane = tid & 63, w = tid >> 6, i16 = lane & 15, q = lane >> 4;
    f32x4 z = {0.f,0.f,0.f,0.f};
    f32x4 acc[2][4] = {{z,z,z,z},{z,z,z,z}};
    const size_t GLS = (size_t)4 * 4096 * 128;   // per-layer stride in G (elems)
    const bf16_t* gb = G + ((size_t)n * 4096 + t0) * 128 + tid * 8;
    int fi0 = (2 * w) * 256 + lane;       // fragment row base for out-row pair 2w
    int fi1 = fi0 + 256;                  // 2w+1
    // Askp fragment regs (layer parity: akA=even layers, akB=odd)
    bf16x8 akA[8], akB[8];
    {
        const bf16x8* A0 = (const bf16x8*)Askp;
        #pragma unroll
        for (int kb = 0; kb < 4; ++kb) {
            akA[2 * kb]     = A0[fi0 + kb * 64];
            akA[2 * kb + 1] = A0[fi1 + kb * 64];
        }
    }
    // G regs: gA written at even iters (odd layers), gB at odd iters (even layers)
    i32x4 gA0, gA1, gB0, gB1;
    {
        i32x4 t0v = *(const i32x4*)(gb);
        i32x4 t1v = *(const i32x4*)(gb + 4096);
        *(i32x4*)(gbuf[0] + tid * 8) = t0v;
        *(i32x4*)(gbuf[0] + 4096 + tid * 8) = t1v;
    }
    gA0 = *(const i32x4*)(gb + 1 * GLS);
    gA1 = *(const i32x4*)(gb + 1 * GLS + 4096);
    gB0 = *(const i32x4*)(gb + 2 * GLS);
    gB1 = *(const i32x4*)(gb + 2 * GLS + 4096);
    __syncthreads();   // prologue: single full drain
    #pragma unroll 1
    for (int ii = 0; ii < 30; ii += 2) {
        SKIP_HALF(ii,     akA, akB, gA0, gA1)
        SKIP_HALF(ii + 1, akB, akA, gB0, gB1)
    }
    float* sp = sbuf + (size_t)n * 256 * 4096 + t0;
    #pragma unroll
    for (int mt2 = 0; mt2 < 2; ++mt2)
        #pragma unroll
        for (int nt = 0; nt < 4; ++nt)
            #pragma unroll
            for (int j = 0; j < 4; ++j) {
                int o = (2 * w + mt2) * 16 + q * 4 + j;
                sp[(size_t)o * 4096 + nt * 16 + i16] += acc[mt2][nt][j];
            }
}

// ---------------- end: out = relu(end1@relu(s) + b1 + cond2_tiled) ----------------
__global__ __launch_bounds__(512) void k_end(
    const float* __restrict__ sbuf, float* __restrict__ out,
    const bf16_t* __restrict__ Ae, const float* __restrict__ cond2,
    const float* __restrict__ b1)
{
    __shared__ __align__(16) bf16_t st[64 * PX];
    __shared__ float c2[4096];
    __shared__ float b1s[256];
    int tid = threadIdx.x;
    int n = blockIdx.y, t0 = blockIdx.x * 64;
    int lane = tid & 63, w = tid >> 6, i16 = lane & 15, q = lane >> 4;
    f32x4 z = {0.f,0.f,0.f,0.f};
    {
        int t = tid & 63;
        for (int c = tid >> 6; c < 256; c += 8) {
            float v = sbuf[((size_t)n * 256 + c) * 4096 + t0 + t];
            st[t * PX + c] = (bf16_t)fmaxf(v, 0.f);
        }
        const f32x4* cc = (const f32x4*)(cond2 + (size_t)n * 4096);
        for (int idx = tid; idx < 1024; idx += 512) ((f32x4*)c2)[idx] = cc[idx];
        if (tid < 64) ((f32x4*)b1s)[tid] = ((const f32x4*)b1)[tid];
    }
    __syncthreads();
    f32x4 acc[2][4] = {{z,z,z,z},{z,z,z,z}};
    #pragma unroll
    for (int kb = 0; kb < 8; ++kb) {
        int koff = kb * 32 + q * 8;
        bf16x8 bf[4];
        #pragma unroll
        for (int nt = 0; nt < 4; ++nt)
            bf[nt] = *(const bf16x8*)(st + (nt * 16 + i16) * PX + koff);
        #pragma unroll
        for (int mt2 = 0; mt2 < 2; ++mt2) {
            bf16x8 af = *(const bf16x8*)(Ae + ((((size_t)2 * w + mt2) * 8 + kb) * 64 + lane) * 8);
            #pragma unroll
            for (int nt = 0; nt < 4; ++nt) acc[mt2][nt] = mfma16(af, bf[nt], acc[mt2][nt]);
        }
    }
    #pragma unroll
    for (int mt2 = 0; mt2 < 2; ++mt2)
        #pragma unroll
        for (int j = 0; j < 4; ++j) {
            int o = (2 * w + mt2) * 16 + q * 4 + j;
            float bb = b1s[o] + c2[o * 16 + i16];
            #pragma unroll
            for (int nt = 0; nt < 4; ++nt) {
                float v = acc[mt2][nt][j] + bb;
                out[((size_t)n * 256 + o) * 4096 + t0 + nt * 16 + i16] = fmaxf(v, 0.f);
            }
        }
}

extern "C" void kernel_launch(void* const* d_in, const int* in_sizes, int n_in,
                              void* d_out, int out_size, void* d_ws, size_t ws_size,
                              hipStream_t stream) {
    const float* x   = (const float*)d_in[0];
    const float* en  = (const float*)d_in[1];
    const float* s1w = (const float*)d_in[2];
    const float* s2w = (const float*)d_in[3];
    const float* cw  = (const float*)d_in[4];
    const float* dw  = (const float*)d_in[5];
    const float* rw  = (const float*)d_in[6];
    const float* kw  = (const float*)d_in[7];
    const float* e1w = (const float*)d_in[8];
    const float* e1b = (const float*)d_in[9];
    const float* e2w = (const float*)d_in[10];
    const float* e2b = (const float*)d_in[11];
    float* out = (float*)d_out;

    char* p = (char*)d_ws;
    auto take = [&](size_t bytes) {
        char* r = p;
        p += (bytes + 255) & ~(size_t)255;
        return r;
    };
    bf16_t* A1   = (bf16_t*)take((size_t)128 * 256 * 2);
    bf16_t* A2   = (bf16_t*)take((size_t)256 * 128 * 2);
    bf16_t* Ae   = (bf16_t*)take((size_t)256 * 256 * 2);
    bf16_t* Adil = (bf16_t*)take((size_t)30 * 65536 * 2);
    bf16_t* Ares = (bf16_t*)take((size_t)30 * 16384 * 2);
    bf16_t* Askp = (bf16_t*)take((size_t)30 * 32768 * 2);
    float*  condA= (float*)take((size_t)30 * 16384 * 4);
    float*  cond2= (float*)take((size_t)16384 * 4);
    bf16_t* la   = (bf16_t*)take((size_t)4 * 8192 * 128 * 2);
    bf16_t* lb   = (bf16_t*)take((size_t)4 * 8192 * 128 * 2);
    float*  sbuf = (float*)take((size_t)4 * 256 * 4096 * 4);
    bf16_t* G    = (bf16_t*)take((size_t)30 * 4 * 4096 * 128 * 2);  // last
    bool useG = ((size_t)(p - (char*)d_ws) <= ws_size);

    k_prep<<<2240, 256, 0, stream>>>(rw, kw, s1w, s2w, e1w, dw,
                                     cw, e2w, e2b, en,
                                     Ares, Askp, A1, A2, Ae, Adil, condA, cond2);

    // causal trim table (host)
    int a[30];
    a[29] = 4096;
    for (int i = 28; i >= 0; --i) {
        int nx = a[i + 1] - (1 << ((i + 1) % 10));
        a[i] = nx < 4096 ? (nx & ~63) : 4096;
    }

    k_start<<<dim3(127, 4), 512, 0, stream>>>(x, la, sbuf, A1, A2, 64);

    bf16_t* src = la;
    bf16_t* dst = lb;
    for (int i = 0; i < 30; ++i) {
        dim3 grid((8192 - a[i]) / 32, 4);
        if (useG)
            k_layer<1><<<grid, 512, 0, stream>>>(src, dst, sbuf,
                G + (size_t)i * 4 * 4096 * 128,
                Adil + (size_t)i * 65536, Ares + (size_t)i * 16384,
                Askp + (size_t)i * 32768, condA + (size_t)i * 16384,
                1 << (i % 10), a[i], i < 29 ? 1 : 0);
        else
            k_layer<0><<<grid, 512, 0, stream>>>(src, dst, sbuf, (bf16_t*)nullptr,
                Adil + (size_t)i * 65536, Ares + (size_t)i * 16384,
                Askp + (size_t)i * 32768, condA + (size_t)i * 16384,
                1 << (i % 10), a[i], i < 29 ? 1 : 0);
        bf16_t* t = src; src = dst; dst = t;
    }
    if (useG)
        k_skip<<<dim3(64, 4), 512, 0, stream>>>(G, sbuf, Askp);
    k_end<<<dim3(64, 4), 512, 0, stream>>>(sbuf, out, Ae, cond2, e1b);
}